// Round 17
// baseline (354.933 us; speedup 1.0000x reference)
//
#include <hip/hip_runtime.h>

typedef __attribute__((ext_vector_type(4))) float f32x4;
typedef __attribute__((ext_vector_type(8))) short short8x;
typedef __attribute__((ext_vector_type(4))) unsigned short u16x4;

#define DIM   4096
#define NB    8
#define NN    2048
#define NROWS (NB*NN)
#define NQ    7
#define NHQ   56
#define SCALE 0.04419417382415922f  /* 1/sqrt(512) */

// ---- workspace layout (float offsets); xbf high region ~174 MB total
#define OFF_MU     0L
#define OFF_RSTD   16384L
#define OFF_Q7     32768L
#define OFF_A      61440L
#define OFF_D0     61504L
#define OFF_S1     61568L
#define OFF_SUMEXP 61632L
#define OFF_CTXM   62528L
#define OFF_GFIN   95296L
#define OFF_YM     128064L
#define OFF_UGBF   390208L
#define OFF_SCT    521280L
#define OFF_BIG    1438784L
#define OFF_PART   (OFF_BIG)
#define OFF_XBF    10000000L

__device__ __forceinline__ unsigned short f2bf(float f) {   // RNE
  union { float f; unsigned int u; } v; v.f = f;
  return (unsigned short)((v.u + 0x7FFFu + ((v.u >> 16) & 1u)) >> 16);
}
__device__ __forceinline__ unsigned short f2bfr(float f) {  // cheap round
  union { float f; unsigned int u; } v; v.f = f;
  return (unsigned short)((v.u + 0x8000u) >> 16);
}
__device__ __forceinline__ float bf2f(unsigned short u) {
  return __uint_as_float((unsigned)u << 16);
}
__device__ __forceinline__ f32x4 ntl4(const float* p) {
  return __builtin_nontemporal_load((const f32x4*)p);
}
__device__ __forceinline__ void nts4(float* p, f32x4 v) {
  __builtin_nontemporal_store(v, (f32x4*)p);
}
__device__ __forceinline__ float waveSum(float v) {
  #pragma unroll
  for (int m = 1; m < 64; m <<= 1) v += __shfl_xor(v, m);
  return v;
}

// ---- K1: qproj (+ zero sumexp/s1/A/D0 and ugbf pad rows)
__global__ __launch_bounds__(256) void k_pre(const float* __restrict__ ipw,
    const float* __restrict__ ipb, const float* __restrict__ slots,
    float* __restrict__ q7, float* __restrict__ ws) {
  const int bid = blockIdx.x, tid = threadIdx.x;
  const int w = tid >> 6, l = tid & 63;
  if (bid == 0) {
    if (tid < 448) (ws + OFF_SUMEXP)[tid] = 0.f;
    else if (tid < 512) (ws + OFF_S1)[tid - 448] = 0.f;
  } else if (bid <= 8) {
    unsigned* u32 = (unsigned*)(ws + OFF_UGBF);
    const long r = 56 + bid - 1;
    #pragma unroll
    for (int j = 0; j < 8; j++) u32[r*2048 + (long)tid*8 + j] = 0u;
  } else if (bid == 9) {
    if (tid < 64) (ws + OFF_A)[tid] = 0.f;
    else if (tid < 128) (ws + OFF_D0)[tid - 64] = 0.f;
  }
  const int d = bid * 4 + w;
  const float* wr = ipw + (long)d * DIM;
  float acc[7] = {0,0,0,0,0,0,0};
  for (int e4 = l; e4 < 1024; e4 += 64) {
    f32x4 wv = ntl4(wr + e4*4);
    #pragma unroll
    for (int s = 0; s < 7; s++) {
      float4 sv = ((const float4*)(slots + (long)s*DIM))[e4];
      sv.x = fminf(fmaxf(sv.x, -10.f), 10.f); sv.y = fminf(fmaxf(sv.y, -10.f), 10.f);
      sv.z = fminf(fmaxf(sv.z, -10.f), 10.f); sv.w = fminf(fmaxf(sv.w, -10.f), 10.f);
      acc[s] += wv.x*sv.x + wv.y*sv.y + wv.z*sv.z + wv.w*sv.w;
    }
  }
  #pragma unroll
  for (int s = 0; s < 7; s++) acc[s] = waveSum(acc[s]);
  if (l == 0) {
    float bq = ipb[d];
    #pragma unroll
    for (int s = 0; s < 7; s++) q7[(long)s*DIM + d] = acc[s] + bq;
  }
}

// ---- K2: uproj partials + D0 bk-term atomics (bx==0 blocks)
__global__ __launch_bounds__(256) void k_uproj(const float* __restrict__ ipw,
    const float* __restrict__ ipb, const float* __restrict__ q7,
    float* __restrict__ upart, float* __restrict__ D0arr) {
  __shared__ float qs[7][32];
  const int bid = blockIdx.x, tid = threadIdx.x;
  const int bx = bid & 3, h = (bid >> 2) & 7, c = bid >> 5;
  if (tid < 224) {
    int s = tid >> 5, hd = tid & 31;
    qs[s][hd] = q7[(long)s*DIM + h*512 + c*32 + hd];
  }
  __syncthreads();
  if (bx == 0 && tid < 64) {
    const int l = tid;
    float bk = (l < 32) ? ipb[DIM + h*512 + c*32 + l] : 0.f;
    #pragma unroll
    for (int s = 0; s < 7; s++) {
      float v = (l < 32) ? qs[s][l]*bk : 0.f;
      v = waveSum(v);
      if (l == 0) atomicAdd(&D0arr[h*7 + s], SCALE * v);
    }
  }
  const int e0 = bx*1024 + tid*4;
  float4 acc[7];
  #pragma unroll
  for (int s = 0; s < 7; s++) { acc[s].x = 0; acc[s].y = 0; acc[s].z = 0; acc[s].w = 0; }
  #pragma unroll 4
  for (int hd = 0; hd < 32; hd++) {
    f32x4 wv = ntl4(ipw + ((long)(DIM + h*512 + c*32 + hd))*DIM + e0);
    #pragma unroll
    for (int s = 0; s < 7; s++) {
      float qv = qs[s][hd];
      acc[s].x += qv*wv.x; acc[s].y += qv*wv.y; acc[s].z += qv*wv.z; acc[s].w += qv*wv.w;
    }
  }
  #pragma unroll
  for (int s = 0; s < 7; s++)
    *(float4*)&upart[(long)((c*8 + h)*7 + s)*DIM + e0] = acc[s];
}

// ---- K3: u = SCALE*sum_c upart; ugbf = bf16(u*ln_g); A/D0 atomics
__global__ __launch_bounds__(256) void k_ured(const float* __restrict__ upart,
    const float* __restrict__ lng, const float* __restrict__ lnb,
    unsigned short* __restrict__ ugbf, float* __restrict__ Aarr, float* __restrict__ D0arr) {
  const int bid = blockIdx.x, tid = threadIdx.x;
  const int bx = bid & 15, h = bid >> 4;
  const int e = bx*256 + tid, l = tid & 63;
  float ge = lng[e], be = lnb[e];
  #pragma unroll
  for (int s = 0; s < 7; s++) {
    float u = 0;
    #pragma unroll
    for (int c = 0; c < 16; c++) u += upart[(long)((c*8 + h)*7 + s)*DIM + e];
    u *= SCALE;
    ugbf[(long)(h*7 + s)*DIM + e] = f2bf(u * ge);
    float pa = waveSum(u * ge);
    float pd = waveSum(u * be);
    if (l == 0) {
      atomicAdd(&Aarr[h*7 + s], pa);
      atomicAdd(&D0arr[h*7 + s], pd);
    }
  }
}

// ---- K4: staged scores, WAVE-OWNS-QUADRANT: wave w accumulates hq rows
// [w*16, w*16+16) over FULL K with 4 independent k-offset accumulators.
// No LDS accumulator exchange; epilogue runs on all 4 waves in parallel.
__global__ __launch_bounds__(256) void k_scores(const float* __restrict__ x,
    const unsigned short* __restrict__ ugbf, const float* __restrict__ Aarr,
    const float* __restrict__ D0arr, float* __restrict__ mu_o, float* __restrict__ rstd_o,
    float* __restrict__ sct, float* __restrict__ sumexp, unsigned short* __restrict__ xbf) {
  __shared__ __align__(16) unsigned short xs[16][520];   // 512 + 8 pad
  __shared__ float sred[16][2];
  const int tid = threadIdx.x;
  const int w = tid >> 6, l = tid & 63;
  const int lr = l & 15, lk8 = (l >> 4) * 8;
  const int row0 = blockIdx.x * 16;
  const int b = blockIdx.x >> 7;
  const int r = tid >> 4, c = tid & 15;       // load mapping: row r, col-slot c
  const long xrow = (long)(row0 + r) * DIM;
  const long bq = (long)(w*16 + lr) * DIM;    // my quadrant's B row
  f32x4 acc0 = {0,0,0,0}, acc1 = {0,0,0,0}, acc2 = {0,0,0,0}, acc3 = {0,0,0,0};
  float sx = 0.f, sxx = 0.f;
  for (int s = 0; s < 8; s++) {
    const int kc0 = s * 512;
    f32x4 v[8];
    #pragma unroll
    for (int j = 0; j < 8; j++)
      v[j] = ntl4(x + xrow + kc0 + j*64 + c*4);
    #pragma unroll
    for (int j = 0; j < 8; j++) {
      sx  += (v[j].x + v[j].y) + (v[j].z + v[j].w);
      sxx += v[j].x*v[j].x + v[j].y*v[j].y + v[j].z*v[j].z + v[j].w*v[j].w;
      u16x4 a;
      a.x = f2bfr(v[j].x); a.y = f2bfr(v[j].y);
      a.z = f2bfr(v[j].z); a.w = f2bfr(v[j].w);
      *(u16x4*)&xs[r][j*64 + c*4] = a;
      *(u16x4*)(xbf + xrow + kc0 + j*64 + c*4) = a;
    }
    __syncthreads();
    #pragma unroll
    for (int kk = 0; kk < 512; kk += 128) {
      short8x a0 = *(const short8x*)&xs[lr][kk + 0  + lk8];
      short8x c0 = *(const short8x*)(ugbf + bq + kc0 + kk + 0  + lk8);
      acc0 = __builtin_amdgcn_mfma_f32_16x16x32_bf16(a0, c0, acc0, 0, 0, 0);
      short8x a1 = *(const short8x*)&xs[lr][kk + 32 + lk8];
      short8x c1 = *(const short8x*)(ugbf + bq + kc0 + kk + 32 + lk8);
      acc1 = __builtin_amdgcn_mfma_f32_16x16x32_bf16(a1, c1, acc1, 0, 0, 0);
      short8x a2 = *(const short8x*)&xs[lr][kk + 64 + lk8];
      short8x c2 = *(const short8x*)(ugbf + bq + kc0 + kk + 64 + lk8);
      acc2 = __builtin_amdgcn_mfma_f32_16x16x32_bf16(a2, c2, acc2, 0, 0, 0);
      short8x a3 = *(const short8x*)&xs[lr][kk + 96 + lk8];
      short8x c3 = *(const short8x*)(ugbf + bq + kc0 + kk + 96 + lk8);
      acc3 = __builtin_amdgcn_mfma_f32_16x16x32_bf16(a3, c3, acc3, 0, 0, 0);
    }
    __syncthreads();
  }
  // merge the 4 k-offset partials in-register
  f32x4 accS;
  #pragma unroll
  for (int i = 0; i < 4; i++) accS[i] = (acc0[i] + acc1[i]) + (acc2[i] + acc3[i]);
  // stats: reduce over c (low 4 lane bits); lane c==0 holds row r totals
  #pragma unroll
  for (int m = 1; m <= 8; m <<= 1) { sx += __shfl_xor(sx, m); sxx += __shfl_xor(sxx, m); }
  if (c == 0) { sred[r][0] = sx; sred[r][1] = sxx; }
  __syncthreads();
  float muv = sred[lr][0] * (1.0f/DIM);
  float var = sred[lr][1] * (1.0f/DIM) - muv*muv;
  float rsv = rsqrtf(var + 1e-5f);
  if (w == 0 && l < 16) { mu_o[row0 + l] = muv; rstd_o[row0 + l] = rsv; }
  const int hq = w*16 + lr;
  float es = 0.f;
  if (hq < NHQ) {
    const float Ah = Aarr[hq], Dh = D0arr[hq];
    #pragma unroll
    for (int i = 0; i < 4; i++) {
      const int rl = (l >> 4)*4 + i;
      const float mur_ = __shfl(muv, rl);
      const float rs_  = __shfl(rsv, rl);
      float e = __expf(rs_*(accS[i] - mur_*Ah) + Dh);
      sct[(long)hq*NROWS + row0 + rl] = e;
      es += e;
    }
  }
  es += __shfl_xor(es, 16); es += __shfl_xor(es, 32);
  if (l < 16 && (w*16 + l) < NHQ)
    atomicAdd(&sumexp[b*NHQ + w*16 + l], es);
}

// ---- K5: ypart reading bf16 xbf; ec==0 also emits out_attn + s1
__global__ __launch_bounds__(256) void k_ypart(const unsigned short* __restrict__ xbf,
    const float* __restrict__ sct, const float* __restrict__ sumexp,
    const float* __restrict__ mu, const float* __restrict__ rstd,
    float* __restrict__ part, float* __restrict__ s1, float* __restrict__ out_attn) {
  __shared__ float rinv[56];
  __shared__ float amr[8][128];
  __shared__ float psm[56][128];
  const int bid = blockIdx.x, tid = threadIdx.x;
  const int b = bid >> 6, ec = (bid >> 4) & 3, nc = bid & 15;
  const int row0 = b*NN + nc*128;
  if (tid < 56) rinv[tid] = 1.0f / sumexp[b*NHQ + tid];
  __syncthreads();
  for (int i = tid; i < 1024; i += 256) {
    const int h = i >> 7, nn = i & 127, row = row0 + nn;
    float amv = 0;
    #pragma unroll
    for (int q = 0; q < 7; q++) {
      float p = sct[(long)(h*7 + q)*NROWS + row] * rinv[h*7 + q];
      amv += p;
      psm[h*7 + q][nn] = p;
    }
    amv *= (1.0f/7.0f);
    amr[h][nn] = amv * rstd[row];
  }
  __syncthreads();
  if (ec == 0) {
    for (int i = tid; i < 896; i += 256) {
      const int q = i / 128, nn = i % 128;
      float s = 0;
      #pragma unroll
      for (int h = 0; h < 8; h++) s += psm[h*7 + q][nn];
      out_attn[((long)(b*NQ + q))*NN + nc*128 + nn] = s * 0.125f;
    }
    {
      const int h = tid >> 5, sl = tid & 31;
      float v = 0;
      #pragma unroll
      for (int nn = sl; nn < 128; nn += 32) v += amr[h][nn] * mu[row0 + nn];
      #pragma unroll
      for (int m = 1; m < 32; m <<= 1) v += __shfl_xor(v, m);
      if (sl == 0) atomicAdd(&s1[b*8 + h], v);
    }
  }
  const int e = ec*1024 + tid*4;
  float ax[8], ay[8], az[8], aw[8];
  #pragma unroll
  for (int h = 0; h < 8; h++) { ax[h]=0; ay[h]=0; az[h]=0; aw[h]=0; }
  const unsigned short* xp = xbf + (long)row0*DIM + e;
  #pragma unroll 2
  for (int nn = 0; nn < 128; nn++) {
    const u16x4 xv = *(const u16x4*)(xp + (long)nn*DIM);
    const float xx = bf2f(xv.x), xy = bf2f(xv.y), xz = bf2f(xv.z), xw = bf2f(xv.w);
    #pragma unroll
    for (int h = 0; h < 8; h++) {
      float a = amr[h][nn];
      ax[h] += a*xx; ay[h] += a*xy; az[h] += a*xz; aw[h] += a*xw;
    }
  }
  #pragma unroll
  for (int h = 0; h < 8; h++) {
    float4 o; o.x = ax[h]; o.y = ay[h]; o.z = az[h]; o.w = aw[h];
    *(float4*)&part[((long)(nc*64 + b*8 + h))*DIM + e] = o;
  }
}

// ---- K6: reduce 16 partials; ym = lng*(y - s1) + lnb
__global__ __launch_bounds__(256) void k_yred(const float* __restrict__ part,
    const float* __restrict__ s1, const float* __restrict__ lng, const float* __restrict__ lnb,
    float* __restrict__ ym) {
  const long i4 = (long)blockIdx.x*256 + threadIdx.x;
  const float4* p4 = (const float4*)part;
  float4 s = p4[i4];
  #pragma unroll
  for (int nc = 1; nc < 16; nc++) {
    float4 v = p4[(long)nc*65536 + i4];
    s.x += v.x; s.y += v.y; s.z += v.z; s.w += v.w;
  }
  const int bh = (int)(i4 >> 10), e4 = (int)(i4 & 1023);
  float sv = s1[bh];
  float4 g = ((const float4*)lng)[e4], bb = ((const float4*)lnb)[e4];
  float4 o;
  o.x = g.x*(s.x - sv) + bb.x; o.y = g.y*(s.y - sv) + bb.y;
  o.z = g.z*(s.z - sv) + bb.z; o.w = g.w*(s.w - sv) + bb.w;
  ((float4*)ym)[i4] = o;
}

// ---- K7: ctxm[b][d] = Wv_row(d).ym[b, d>>9, :] + bv[d]
__global__ __launch_bounds__(256) void k_ctxm(const float* __restrict__ ipw,
    const float* __restrict__ ipb, const float* __restrict__ ym, float* __restrict__ ctxm) {
  const int w = threadIdx.x >> 6, l = threadIdx.x & 63;
  const int d = blockIdx.x*4 + w;
  const int h = d >> 9;
  const float* wr = ipw + ((long)(2*DIM + d))*DIM;
  float acc[8] = {0,0,0,0,0,0,0,0};
  for (int e4 = l; e4 < 1024; e4 += 64) {
    f32x4 wv = ntl4(wr + e4*4);
    #pragma unroll
    for (int b = 0; b < 8; b++) {
      float4 y = ((const float4*)(ym + (long)(b*8 + h)*DIM))[e4];
      acc[b] += wv.x*y.x + wv.y*y.y + wv.z*y.z + wv.w*y.w;
    }
  }
  #pragma unroll
  for (int b = 0; b < 8; b++) acc[b] = waveSum(acc[b]);
  if (l == 0) {
    float bias = ipb[2*DIM + d];
    #pragma unroll
    for (int b = 0; b < 8; b++) ctxm[(long)b*DIM + d] = acc[b] + bias;
  }
}

// ---- K8: gfin[b][d] = tanh(alpha)*(sm[d] + opw_row(d).ctxm[b] + opb[d])
__global__ __launch_bounds__(256) void k_gvec(const float* __restrict__ opw,
    const float* __restrict__ opb, const float* __restrict__ ctxm, const float* __restrict__ slots,
    const float* __restrict__ alpha, float* __restrict__ gfin) {
  const int w = threadIdx.x >> 6, l = threadIdx.x & 63;
  const int d = blockIdx.x*4 + w;
  const float* wr = opw + (long)d*DIM;
  float acc[8] = {0,0,0,0,0,0,0,0};
  for (int e4 = l; e4 < 1024; e4 += 64) {
    f32x4 wv = ntl4(wr + e4*4);
    #pragma unroll
    for (int b = 0; b < 8; b++) {
      float4 c = ((const float4*)(ctxm + (long)b*DIM))[e4];
      acc[b] += wv.x*c.x + wv.y*c.y + wv.z*c.z + wv.w*c.w;
    }
  }
  #pragma unroll
  for (int b = 0; b < 8; b++) acc[b] = waveSum(acc[b]);
  if (l == 0) {
    float smv = 0;
    #pragma unroll
    for (int q = 0; q < 7; q++)
      smv += fminf(fmaxf(slots[(long)q*DIM + d], -10.f), 10.f);
    smv *= (1.0f/7.0f);
    float t = tanhf(alpha[0]);
    float base = smv + opb[d];
    #pragma unroll
    for (int b = 0; b < 8; b++) gfin[(long)b*DIM + d] = t * (base + acc[b]);
  }
}

// ---- K9: x_refined = bf16x + g[b]  (16B xbf loads, nt-stores out)
__global__ __launch_bounds__(256) void k_refine(const unsigned short* __restrict__ xbf,
    const float* __restrict__ gfin, float* __restrict__ out) {
  const float4* g4 = (const float4*)gfin;
  const long total8 = (long)NROWS * 512;   // 8-float units
  for (long i8 = (long)blockIdx.x*256 + threadIdx.x; i8 < total8; i8 += (long)gridDim.x*256) {
    const long b = i8 >> 20;               // 2048*4096/8 = 2^20 units per batch
    const int e8 = (int)(i8 & 511);
    const short8x xv = *(const short8x*)(xbf + i8*8);
    const float4 g0 = g4[b*1024 + e8*2], g1 = g4[b*1024 + e8*2 + 1];
    f32x4 o0, o1;
    o0.x = bf2f((unsigned short)xv[0]) + g0.x;
    o0.y = bf2f((unsigned short)xv[1]) + g0.y;
    o0.z = bf2f((unsigned short)xv[2]) + g0.z;
    o0.w = bf2f((unsigned short)xv[3]) + g0.w;
    o1.x = bf2f((unsigned short)xv[4]) + g1.x;
    o1.y = bf2f((unsigned short)xv[5]) + g1.y;
    o1.z = bf2f((unsigned short)xv[6]) + g1.z;
    o1.w = bf2f((unsigned short)xv[7]) + g1.w;
    nts4(out + i8*8,     o0);
    nts4(out + i8*8 + 4, o1);
  }
}

extern "C" void kernel_launch(void* const* d_in, const int* in_sizes, int n_in,
                              void* d_out, int out_size, void* d_ws, size_t ws_size,
                              hipStream_t stream) {
  const float* x     = (const float*)d_in[0];
  const float* slots = (const float*)d_in[1];
  const float* lng   = (const float*)d_in[2];
  const float* lnb   = (const float*)d_in[3];
  const float* ipw   = (const float*)d_in[4];
  const float* ipb   = (const float*)d_in[5];
  const float* opw   = (const float*)d_in[6];
  const float* opb   = (const float*)d_in[7];
  const float* alpha = (const float*)d_in[8];
  float* out = (float*)d_out;
  float* ws  = (float*)d_ws;

  float* mu     = ws + OFF_MU;
  float* rstd   = ws + OFF_RSTD;
  float* q7     = ws + OFF_Q7;
  float* Aarr   = ws + OFF_A;
  float* D0arr  = ws + OFF_D0;
  float* s1     = ws + OFF_S1;
  float* sumexp = ws + OFF_SUMEXP;
  float* ctxm   = ws + OFF_CTXM;
  float* gfin   = ws + OFF_GFIN;
  float* ym     = ws + OFF_YM;
  unsigned short* ugbf = (unsigned short*)(ws + OFF_UGBF);
  float* sct    = ws + OFF_SCT;
  float* upart  = ws + OFF_BIG;
  float* part   = ws + OFF_PART;
  unsigned short* xbf = (unsigned short*)(ws + OFF_XBF);
  float* out_attn = out + (long)NROWS * DIM;

  hipLaunchKernelGGL(k_pre,    dim3(1024), dim3(256), 0, stream, ipw, ipb, slots, q7, ws);
  hipLaunchKernelGGL(k_uproj,  dim3(512),  dim3(256), 0, stream, ipw, ipb, q7, upart, D0arr);
  hipLaunchKernelGGL(k_ured,   dim3(128),  dim3(256), 0, stream, upart, lng, lnb, ugbf, Aarr, D0arr);
  hipLaunchKernelGGL(k_scores, dim3(1024), dim3(256), 0, stream, x, ugbf, Aarr, D0arr, mu, rstd, sct, sumexp, xbf);
  hipLaunchKernelGGL(k_ypart,  dim3(512),  dim3(256), 0, stream, xbf, sct, sumexp, mu, rstd, part, s1, out_attn);
  hipLaunchKernelGGL(k_yred,   dim3(256),  dim3(256), 0, stream, part, s1, lng, lnb, ym);
  hipLaunchKernelGGL(k_ctxm,   dim3(1024), dim3(256), 0, stream, ipw, ipb, ym, ctxm);
  hipLaunchKernelGGL(k_gvec,   dim3(1024), dim3(256), 0, stream, opw, opb, ctxm, slots, alpha, gfin);
  hipLaunchKernelGGL(k_refine, dim3(8192), dim3(256), 0, stream, xbf, gfin, out);
}

// Round 18
// 347.034 us; speedup vs baseline: 1.0228x; 1.0228x over previous
//
#include <hip/hip_runtime.h>

typedef __attribute__((ext_vector_type(4))) float f32x4;
typedef __attribute__((ext_vector_type(8))) short short8x;
typedef __attribute__((ext_vector_type(4))) unsigned short u16x4;

#define DIM   4096
#define NB    8
#define NN    2048
#define NROWS (NB*NN)
#define NQ    7
#define NHQ   56
#define SCALE 0.04419417382415922f  /* 1/sqrt(512) */

// ---- workspace layout (float offsets); xbf high region ~174 MB total
#define OFF_MU     0L
#define OFF_RSTD   16384L
#define OFF_Q7     32768L
#define OFF_A      61440L
#define OFF_D0     61504L
#define OFF_S1     61568L
#define OFF_SUMEXP 61632L
#define OFF_CTXM   62528L
#define OFF_GFIN   95296L
#define OFF_YM     128064L
#define OFF_UGBF   390208L
#define OFF_SCT    521280L
#define OFF_BIG    1438784L
#define OFF_PART   (OFF_BIG)
#define OFF_XBF    10000000L

__device__ __forceinline__ unsigned short f2bf(float f) {   // RNE
  union { float f; unsigned int u; } v; v.f = f;
  return (unsigned short)((v.u + 0x7FFFu + ((v.u >> 16) & 1u)) >> 16);
}
__device__ __forceinline__ unsigned short f2bfr(float f) {  // cheap round
  union { float f; unsigned int u; } v; v.f = f;
  return (unsigned short)((v.u + 0x8000u) >> 16);
}
__device__ __forceinline__ float bf2f(unsigned short u) {
  return __uint_as_float((unsigned)u << 16);
}
__device__ __forceinline__ f32x4 ntl4(const float* p) {
  return __builtin_nontemporal_load((const f32x4*)p);
}
__device__ __forceinline__ void nts4(float* p, f32x4 v) {
  __builtin_nontemporal_store(v, (f32x4*)p);
}
__device__ __forceinline__ float waveSum(float v) {
  #pragma unroll
  for (int m = 1; m < 64; m <<= 1) v += __shfl_xor(v, m);
  return v;
}

// ---- K1: qproj (+ zero sumexp/s1/A/D0 and ugbf pad rows)
__global__ __launch_bounds__(256) void k_pre(const float* __restrict__ ipw,
    const float* __restrict__ ipb, const float* __restrict__ slots,
    float* __restrict__ q7, float* __restrict__ ws) {
  const int bid = blockIdx.x, tid = threadIdx.x;
  const int w = tid >> 6, l = tid & 63;
  if (bid == 0) {
    if (tid < 448) (ws + OFF_SUMEXP)[tid] = 0.f;
    else if (tid < 512) (ws + OFF_S1)[tid - 448] = 0.f;
  } else if (bid <= 8) {
    unsigned* u32 = (unsigned*)(ws + OFF_UGBF);
    const long r = 56 + bid - 1;
    #pragma unroll
    for (int j = 0; j < 8; j++) u32[r*2048 + (long)tid*8 + j] = 0u;
  } else if (bid == 9) {
    if (tid < 64) (ws + OFF_A)[tid] = 0.f;
    else if (tid < 128) (ws + OFF_D0)[tid - 64] = 0.f;
  }
  const int d = bid * 4 + w;
  const float* wr = ipw + (long)d * DIM;
  float acc[7] = {0,0,0,0,0,0,0};
  for (int e4 = l; e4 < 1024; e4 += 64) {
    f32x4 wv = ntl4(wr + e4*4);
    #pragma unroll
    for (int s = 0; s < 7; s++) {
      float4 sv = ((const float4*)(slots + (long)s*DIM))[e4];
      sv.x = fminf(fmaxf(sv.x, -10.f), 10.f); sv.y = fminf(fmaxf(sv.y, -10.f), 10.f);
      sv.z = fminf(fmaxf(sv.z, -10.f), 10.f); sv.w = fminf(fmaxf(sv.w, -10.f), 10.f);
      acc[s] += wv.x*sv.x + wv.y*sv.y + wv.z*sv.z + wv.w*sv.w;
    }
  }
  #pragma unroll
  for (int s = 0; s < 7; s++) acc[s] = waveSum(acc[s]);
  if (l == 0) {
    float bq = ipb[d];
    #pragma unroll
    for (int s = 0; s < 7; s++) q7[(long)s*DIM + d] = acc[s] + bq;
  }
}

// ---- K2: uproj partials + D0 bk-term atomics (bx==0 blocks)
__global__ __launch_bounds__(256) void k_uproj(const float* __restrict__ ipw,
    const float* __restrict__ ipb, const float* __restrict__ q7,
    float* __restrict__ upart, float* __restrict__ D0arr) {
  __shared__ float qs[7][32];
  const int bid = blockIdx.x, tid = threadIdx.x;
  const int bx = bid & 3, h = (bid >> 2) & 7, c = bid >> 5;
  if (tid < 224) {
    int s = tid >> 5, hd = tid & 31;
    qs[s][hd] = q7[(long)s*DIM + h*512 + c*32 + hd];
  }
  __syncthreads();
  if (bx == 0 && tid < 64) {
    const int l = tid;
    float bk = (l < 32) ? ipb[DIM + h*512 + c*32 + l] : 0.f;
    #pragma unroll
    for (int s = 0; s < 7; s++) {
      float v = (l < 32) ? qs[s][l]*bk : 0.f;
      v = waveSum(v);
      if (l == 0) atomicAdd(&D0arr[h*7 + s], SCALE * v);
    }
  }
  const int e0 = bx*1024 + tid*4;
  float4 acc[7];
  #pragma unroll
  for (int s = 0; s < 7; s++) { acc[s].x = 0; acc[s].y = 0; acc[s].z = 0; acc[s].w = 0; }
  #pragma unroll 4
  for (int hd = 0; hd < 32; hd++) {
    f32x4 wv = ntl4(ipw + ((long)(DIM + h*512 + c*32 + hd))*DIM + e0);
    #pragma unroll
    for (int s = 0; s < 7; s++) {
      float qv = qs[s][hd];
      acc[s].x += qv*wv.x; acc[s].y += qv*wv.y; acc[s].z += qv*wv.z; acc[s].w += qv*wv.w;
    }
  }
  #pragma unroll
  for (int s = 0; s < 7; s++)
    *(float4*)&upart[(long)((c*8 + h)*7 + s)*DIM + e0] = acc[s];
}

// ---- K3: u = SCALE*sum_c upart; ugbf = bf16(u*ln_g); A/D0 atomics
__global__ __launch_bounds__(256) void k_ured(const float* __restrict__ upart,
    const float* __restrict__ lng, const float* __restrict__ lnb,
    unsigned short* __restrict__ ugbf, float* __restrict__ Aarr, float* __restrict__ D0arr) {
  const int bid = blockIdx.x, tid = threadIdx.x;
  const int bx = bid & 15, h = bid >> 4;
  const int e = bx*256 + tid, l = tid & 63;
  float ge = lng[e], be = lnb[e];
  #pragma unroll
  for (int s = 0; s < 7; s++) {
    float u = 0;
    #pragma unroll
    for (int c = 0; c < 16; c++) u += upart[(long)((c*8 + h)*7 + s)*DIM + e];
    u *= SCALE;
    ugbf[(long)(h*7 + s)*DIM + e] = f2bf(u * ge);
    float pa = waveSum(u * ge);
    float pd = waveSum(u * be);
    if (l == 0) {
      atomicAdd(&Aarr[h*7 + s], pa);
      atomicAdd(&D0arr[h*7 + s], pd);
    }
  }
}

// ---- K4: staged scores (R14 verified version). Per 512-float K-chunk:
// coalesced x load -> stats + bf16 (LDS tile + xbf), barrier, 16 MFMA/wave.
__global__ __launch_bounds__(256) void k_scores(const float* __restrict__ x,
    const unsigned short* __restrict__ ugbf, const float* __restrict__ Aarr,
    const float* __restrict__ D0arr, float* __restrict__ mu_o, float* __restrict__ rstd_o,
    float* __restrict__ sct, float* __restrict__ sumexp, unsigned short* __restrict__ xbf) {
  __shared__ __align__(16) unsigned short xs[16][520];   // 512 + 8 pad
  __shared__ float xch[3][64][16];
  __shared__ float sred[16][2];
  const int tid = threadIdx.x;
  const int w = tid >> 6, l = tid & 63;
  const int lr = l & 15, lk8 = (l >> 4) * 8;
  const int row0 = blockIdx.x * 16;
  const int b = blockIdx.x >> 7;
  const int r = tid >> 4, c = tid & 15;       // load mapping: row r, col-slot c
  const long xrow = (long)(row0 + r) * DIM;
  f32x4 acc0 = {0,0,0,0}, acc1 = {0,0,0,0}, acc2 = {0,0,0,0}, acc3 = {0,0,0,0};
  float sx = 0.f, sxx = 0.f;
  const long b0 = (long)(0*16 + lr)*DIM, b1 = (long)(1*16 + lr)*DIM,
             b2 = (long)(2*16 + lr)*DIM, b3 = (long)(3*16 + lr)*DIM;
  for (int s = 0; s < 8; s++) {
    const int kc0 = s * 512;
    f32x4 v[8];
    #pragma unroll
    for (int j = 0; j < 8; j++)
      v[j] = ntl4(x + xrow + kc0 + j*64 + c*4);
    #pragma unroll
    for (int j = 0; j < 8; j++) {
      sx  += (v[j].x + v[j].y) + (v[j].z + v[j].w);
      sxx += v[j].x*v[j].x + v[j].y*v[j].y + v[j].z*v[j].z + v[j].w*v[j].w;
      u16x4 a;
      a.x = f2bfr(v[j].x); a.y = f2bfr(v[j].y);
      a.z = f2bfr(v[j].z); a.w = f2bfr(v[j].w);
      *(u16x4*)&xs[r][j*64 + c*4] = a;
      *(u16x4*)(xbf + xrow + kc0 + j*64 + c*4) = a;
    }
    __syncthreads();
    const long kw = kc0 + w*128;
    #pragma unroll
    for (int kk = 0; kk < 128; kk += 32) {
      short8x a = *(const short8x*)&xs[lr][w*128 + kk + lk8];
      short8x bb0 = *(const short8x*)(ugbf + b0 + kw + kk + lk8);
      acc0 = __builtin_amdgcn_mfma_f32_16x16x32_bf16(a, bb0, acc0, 0, 0, 0);
      short8x bb1 = *(const short8x*)(ugbf + b1 + kw + kk + lk8);
      acc1 = __builtin_amdgcn_mfma_f32_16x16x32_bf16(a, bb1, acc1, 0, 0, 0);
      short8x bb2 = *(const short8x*)(ugbf + b2 + kw + kk + lk8);
      acc2 = __builtin_amdgcn_mfma_f32_16x16x32_bf16(a, bb2, acc2, 0, 0, 0);
      short8x bb3 = *(const short8x*)(ugbf + b3 + kw + kk + lk8);
      acc3 = __builtin_amdgcn_mfma_f32_16x16x32_bf16(a, bb3, acc3, 0, 0, 0);
    }
    __syncthreads();
  }
  // stats: reduce over c (low 4 lane bits); lane c==0 holds row r totals
  #pragma unroll
  for (int m = 1; m <= 8; m <<= 1) { sx += __shfl_xor(sx, m); sxx += __shfl_xor(sxx, m); }
  if (c == 0) { sred[r][0] = sx; sred[r][1] = sxx; }
  if (w != 0) {
    float* p = xch[w - 1][l];
    #pragma unroll
    for (int i = 0; i < 4; i++) {
      p[i] = acc0[i]; p[4+i] = acc1[i]; p[8+i] = acc2[i]; p[12+i] = acc3[i];
    }
  }
  __syncthreads();
  if (w != 0) return;
  #pragma unroll
  for (int ww = 0; ww < 3; ww++) {
    const float* p = xch[ww][l];
    #pragma unroll
    for (int i = 0; i < 4; i++) {
      acc0[i] += p[i]; acc1[i] += p[4+i]; acc2[i] += p[8+i]; acc3[i] += p[12+i];
    }
  }
  float muv = sred[lr][0] * (1.0f/DIM);
  float var = sred[lr][1] * (1.0f/DIM) - muv*muv;
  float rsv = rsqrtf(var + 1e-5f);
  if (l < 16) { mu_o[row0 + l] = muv; rstd_o[row0 + l] = rsv; }
  float es0 = 0, es1 = 0, es2 = 0, es3 = 0;
  #pragma unroll
  for (int i = 0; i < 4; i++) {
    const int rl = (l >> 4)*4 + i;
    const float mur_ = __shfl(muv, rl);
    const float rs_  = __shfl(rsv, rl);
    {
      int hq = 0*16 + lr; float Ah = Aarr[hq], Dh = D0arr[hq];
      float e = __expf(rs_*(acc0[i] - mur_*Ah) + Dh);
      sct[(long)hq*NROWS + row0 + rl] = e; es0 += e;
    }
    {
      int hq = 1*16 + lr; float Ah = Aarr[hq], Dh = D0arr[hq];
      float e = __expf(rs_*(acc1[i] - mur_*Ah) + Dh);
      sct[(long)hq*NROWS + row0 + rl] = e; es1 += e;
    }
    {
      int hq = 2*16 + lr; float Ah = Aarr[hq], Dh = D0arr[hq];
      float e = __expf(rs_*(acc2[i] - mur_*Ah) + Dh);
      sct[(long)hq*NROWS + row0 + rl] = e; es2 += e;
    }
    if (lr < 8) {
      int hq = 3*16 + lr; float Ah = Aarr[hq], Dh = D0arr[hq];
      float e = __expf(rs_*(acc3[i] - mur_*Ah) + Dh);
      sct[(long)hq*NROWS + row0 + rl] = e; es3 += e;
    }
  }
  es0 += __shfl_xor(es0, 16); es0 += __shfl_xor(es0, 32);
  es1 += __shfl_xor(es1, 16); es1 += __shfl_xor(es1, 32);
  es2 += __shfl_xor(es2, 16); es2 += __shfl_xor(es2, 32);
  es3 += __shfl_xor(es3, 16); es3 += __shfl_xor(es3, 32);
  if (l < 16) {
    atomicAdd(&sumexp[b*NHQ + 0*16 + l], es0);
    atomicAdd(&sumexp[b*NHQ + 1*16 + l], es1);
    atomicAdd(&sumexp[b*NHQ + 2*16 + l], es2);
    if (l < 8) atomicAdd(&sumexp[b*NHQ + 3*16 + l], es3);
  }
}

// ---- K5: ypart reading bf16 xbf; ec==0 also emits out_attn + s1
__global__ __launch_bounds__(256) void k_ypart(const unsigned short* __restrict__ xbf,
    const float* __restrict__ sct, const float* __restrict__ sumexp,
    const float* __restrict__ mu, const float* __restrict__ rstd,
    float* __restrict__ part, float* __restrict__ s1, float* __restrict__ out_attn) {
  __shared__ float rinv[56];
  __shared__ float amr[8][128];
  __shared__ float psm[56][128];
  const int bid = blockIdx.x, tid = threadIdx.x;
  const int b = bid >> 6, ec = (bid >> 4) & 3, nc = bid & 15;
  const int row0 = b*NN + nc*128;
  if (tid < 56) rinv[tid] = 1.0f / sumexp[b*NHQ + tid];
  __syncthreads();
  for (int i = tid; i < 1024; i += 256) {
    const int h = i >> 7, nn = i & 127, row = row0 + nn;
    float amv = 0;
    #pragma unroll
    for (int q = 0; q < 7; q++) {
      float p = sct[(long)(h*7 + q)*NROWS + row] * rinv[h*7 + q];
      amv += p;
      psm[h*7 + q][nn] = p;
    }
    amv *= (1.0f/7.0f);
    amr[h][nn] = amv * rstd[row];
  }
  __syncthreads();
  if (ec == 0) {
    for (int i = tid; i < 896; i += 256) {
      const int q = i / 128, nn = i % 128;
      float s = 0;
      #pragma unroll
      for (int h = 0; h < 8; h++) s += psm[h*7 + q][nn];
      out_attn[((long)(b*NQ + q))*NN + nc*128 + nn] = s * 0.125f;
    }
    {
      const int h = tid >> 5, sl = tid & 31;
      float v = 0;
      #pragma unroll
      for (int nn = sl; nn < 128; nn += 32) v += amr[h][nn] * mu[row0 + nn];
      #pragma unroll
      for (int m = 1; m < 32; m <<= 1) v += __shfl_xor(v, m);
      if (sl == 0) atomicAdd(&s1[b*8 + h], v);
    }
  }
  const int e = ec*1024 + tid*4;
  float ax[8], ay[8], az[8], aw[8];
  #pragma unroll
  for (int h = 0; h < 8; h++) { ax[h]=0; ay[h]=0; az[h]=0; aw[h]=0; }
  const unsigned short* xp = xbf + (long)row0*DIM + e;
  #pragma unroll 2
  for (int nn = 0; nn < 128; nn++) {
    const u16x4 xv = *(const u16x4*)(xp + (long)nn*DIM);
    const float xx = bf2f(xv.x), xy = bf2f(xv.y), xz = bf2f(xv.z), xw = bf2f(xv.w);
    #pragma unroll
    for (int h = 0; h < 8; h++) {
      float a = amr[h][nn];
      ax[h] += a*xx; ay[h] += a*xy; az[h] += a*xz; aw[h] += a*xw;
    }
  }
  #pragma unroll
  for (int h = 0; h < 8; h++) {
    float4 o; o.x = ax[h]; o.y = ay[h]; o.z = az[h]; o.w = aw[h];
    *(float4*)&part[((long)(nc*64 + b*8 + h))*DIM + e] = o;
  }
}

// ---- K6: reduce 16 partials; ym = lng*(y - s1) + lnb
__global__ __launch_bounds__(256) void k_yred(const float* __restrict__ part,
    const float* __restrict__ s1, const float* __restrict__ lng, const float* __restrict__ lnb,
    float* __restrict__ ym) {
  const long i4 = (long)blockIdx.x*256 + threadIdx.x;
  const float4* p4 = (const float4*)part;
  float4 s = p4[i4];
  #pragma unroll
  for (int nc = 1; nc < 16; nc++) {
    float4 v = p4[(long)nc*65536 + i4];
    s.x += v.x; s.y += v.y; s.z += v.z; s.w += v.w;
  }
  const int bh = (int)(i4 >> 10), e4 = (int)(i4 & 1023);
  float sv = s1[bh];
  float4 g = ((const float4*)lng)[e4], bb = ((const float4*)lnb)[e4];
  float4 o;
  o.x = g.x*(s.x - sv) + bb.x; o.y = g.y*(s.y - sv) + bb.y;
  o.z = g.z*(s.z - sv) + bb.z; o.w = g.w*(s.w - sv) + bb.w;
  ((float4*)ym)[i4] = o;
}

// ---- K7: ctxm[b][d] = Wv_row(d).ym[b, d>>9, :] + bv[d]
__global__ __launch_bounds__(256) void k_ctxm(const float* __restrict__ ipw,
    const float* __restrict__ ipb, const float* __restrict__ ym, float* __restrict__ ctxm) {
  const int w = threadIdx.x >> 6, l = threadIdx.x & 63;
  const int d = blockIdx.x*4 + w;
  const int h = d >> 9;
  const float* wr = ipw + ((long)(2*DIM + d))*DIM;
  float acc[8] = {0,0,0,0,0,0,0,0};
  for (int e4 = l; e4 < 1024; e4 += 64) {
    f32x4 wv = ntl4(wr + e4*4);
    #pragma unroll
    for (int b = 0; b < 8; b++) {
      float4 y = ((const float4*)(ym + (long)(b*8 + h)*DIM))[e4];
      acc[b] += wv.x*y.x + wv.y*y.y + wv.z*y.z + wv.w*y.w;
    }
  }
  #pragma unroll
  for (int b = 0; b < 8; b++) acc[b] = waveSum(acc[b]);
  if (l == 0) {
    float bias = ipb[2*DIM + d];
    #pragma unroll
    for (int b = 0; b < 8; b++) ctxm[(long)b*DIM + d] = acc[b] + bias;
  }
}

// ---- K8: gfin[b][d] = tanh(alpha)*(sm[d] + opw_row(d).ctxm[b] + opb[d])
__global__ __launch_bounds__(256) void k_gvec(const float* __restrict__ opw,
    const float* __restrict__ opb, const float* __restrict__ ctxm, const float* __restrict__ slots,
    const float* __restrict__ alpha, float* __restrict__ gfin) {
  const int w = threadIdx.x >> 6, l = threadIdx.x & 63;
  const int d = blockIdx.x*4 + w;
  const float* wr = opw + (long)d*DIM;
  float acc[8] = {0,0,0,0,0,0,0,0};
  for (int e4 = l; e4 < 1024; e4 += 64) {
    f32x4 wv = ntl4(wr + e4*4);
    #pragma unroll
    for (int b = 0; b < 8; b++) {
      float4 c = ((const float4*)(ctxm + (long)b*DIM))[e4];
      acc[b] += wv.x*c.x + wv.y*c.y + wv.z*c.z + wv.w*c.w;
    }
  }
  #pragma unroll
  for (int b = 0; b < 8; b++) acc[b] = waveSum(acc[b]);
  if (l == 0) {
    float smv = 0;
    #pragma unroll
    for (int q = 0; q < 7; q++)
      smv += fminf(fmaxf(slots[(long)q*DIM + d], -10.f), 10.f);
    smv *= (1.0f/7.0f);
    float t = tanhf(alpha[0]);
    float base = smv + opb[d];
    #pragma unroll
    for (int b = 0; b < 8; b++) gfin[(long)b*DIM + d] = t * (base + acc[b]);
  }
}

// ---- K9: x_refined = bf16x + g[b]  (reads xbf, nt-stores out)
__global__ __launch_bounds__(256) void k_refine(const unsigned short* __restrict__ xbf,
    const float* __restrict__ gfin, float* __restrict__ out) {
  const float4* g4 = (const float4*)gfin;
  const long total = (long)NROWS * 1024;
  for (long i4 = (long)blockIdx.x*256 + threadIdx.x; i4 < total; i4 += (long)gridDim.x*256) {
    const long b = i4 >> 21;
    const int e4 = (int)(i4 & 1023);
    const u16x4 xv = *(const u16x4*)(xbf + i4*4);
    const float4 gv = g4[b*1024 + e4];
    f32x4 o;
    o.x = bf2f(xv.x) + gv.x; o.y = bf2f(xv.y) + gv.y;
    o.z = bf2f(xv.z) + gv.z; o.w = bf2f(xv.w) + gv.w;
    nts4(out + i4*4, o);
  }
}

extern "C" void kernel_launch(void* const* d_in, const int* in_sizes, int n_in,
                              void* d_out, int out_size, void* d_ws, size_t ws_size,
                              hipStream_t stream) {
  const float* x     = (const float*)d_in[0];
  const float* slots = (const float*)d_in[1];
  const float* lng   = (const float*)d_in[2];
  const float* lnb   = (const float*)d_in[3];
  const float* ipw   = (const float*)d_in[4];
  const float* ipb   = (const float*)d_in[5];
  const float* opw   = (const float*)d_in[6];
  const float* opb   = (const float*)d_in[7];
  const float* alpha = (const float*)d_in[8];
  float* out = (float*)d_out;
  float* ws  = (float*)d_ws;

  float* mu     = ws + OFF_MU;
  float* rstd   = ws + OFF_RSTD;
  float* q7     = ws + OFF_Q7;
  float* Aarr   = ws + OFF_A;
  float* D0arr  = ws + OFF_D0;
  float* s1     = ws + OFF_S1;
  float* sumexp = ws + OFF_SUMEXP;
  float* ctxm   = ws + OFF_CTXM;
  float* gfin   = ws + OFF_GFIN;
  float* ym     = ws + OFF_YM;
  unsigned short* ugbf = (unsigned short*)(ws + OFF_UGBF);
  float* sct    = ws + OFF_SCT;
  float* upart  = ws + OFF_BIG;
  float* part   = ws + OFF_PART;
  unsigned short* xbf = (unsigned short*)(ws + OFF_XBF);
  float* out_attn = out + (long)NROWS * DIM;

  hipLaunchKernelGGL(k_pre,    dim3(1024), dim3(256), 0, stream, ipw, ipb, slots, q7, ws);
  hipLaunchKernelGGL(k_uproj,  dim3(512),  dim3(256), 0, stream, ipw, ipb, q7, upart, D0arr);
  hipLaunchKernelGGL(k_ured,   dim3(128),  dim3(256), 0, stream, upart, lng, lnb, ugbf, Aarr, D0arr);
  hipLaunchKernelGGL(k_scores, dim3(1024), dim3(256), 0, stream, x, ugbf, Aarr, D0arr, mu, rstd, sct, sumexp, xbf);
  hipLaunchKernelGGL(k_ypart,  dim3(512),  dim3(256), 0, stream, xbf, sct, sumexp, mu, rstd, part, s1, out_attn);
  hipLaunchKernelGGL(k_yred,   dim3(256),  dim3(256), 0, stream, part, s1, lng, lnb, ym);
  hipLaunchKernelGGL(k_ctxm,   dim3(1024), dim3(256), 0, stream, ipw, ipb, ym, ctxm);
  hipLaunchKernelGGL(k_gvec,   dim3(1024), dim3(256), 0, stream, opw, opb, ctxm, slots, alpha, gfin);
  hipLaunchKernelGGL(k_refine, dim3(8192), dim3(256), 0, stream, xbf, gfin, out);
}